// Round 1
// baseline (355.759 us; speedup 1.0000x reference)
//
#include <hip/hip_runtime.h>

#define VOCAB 128000
#define EMBED 256
#define BATCH 64
#define TBLOCK 2048
#define ROWS (BATCH * TBLOCK)   // 131072 rows

// One wave (64 lanes) per row: 64 lanes x float4 = 256 floats = one full row.
__global__ __launch_bounds__(256) void embed_expnorm_kernel(
    const int* __restrict__ idx,
    const float* __restrict__ emb,
    float* __restrict__ logits,
    float* __restrict__ probs)
{
    const int gtid = blockIdx.x * blockDim.x + threadIdx.x;
    const int wave = gtid >> 6;        // global wave id == row id
    const int lane = gtid & 63;

    if (wave >= ROWS) return;

    // broadcast row index (all lanes read same address -> single broadcast load)
    const int row = idx[wave];

    // gather one row, float4 per lane (rows are 1KB aligned)
    const float4* rowp = reinterpret_cast<const float4*>(emb + (long long)row * EMBED);
    const float4 v = rowp[lane];

    float4 e;
    e.x = __expf(v.x);
    e.y = __expf(v.y);
    e.z = __expf(v.z);
    e.w = __expf(v.w);

    float s = (e.x + e.y) + (e.z + e.w);
    // 64-lane butterfly reduction
    #pragma unroll
    for (int m = 1; m < 64; m <<= 1)
        s += __shfl_xor(s, m, 64);

    const float inv = 1.0f / s;

    float4 p;
    p.x = e.x * inv;
    p.y = e.y * inv;
    p.z = e.z * inv;
    p.w = e.w * inv;

    const long long off = (long long)wave * (EMBED / 4) + lane;  // float4 units
    reinterpret_cast<float4*>(logits)[off] = v;
    reinterpret_cast<float4*>(probs)[off]  = p;
}

extern "C" void kernel_launch(void* const* d_in, const int* in_sizes, int n_in,
                              void* d_out, int out_size, void* d_ws, size_t ws_size,
                              hipStream_t stream) {
    const int*   idx = (const int*)d_in[0];
    const float* emb = (const float*)d_in[1];

    float* out    = (float*)d_out;
    float* logits = out;                              // [ROWS, EMBED]
    float* probs  = out + (long long)ROWS * EMBED;    // [ROWS, EMBED]

    // 4 waves per 256-thread block -> 4 rows/block
    const int blocks = ROWS / 4;   // 32768
    embed_expnorm_kernel<<<blocks, 256, 0, stream>>>(idx, emb, logits, probs);
}